// Round 11
// baseline (4475.792 us; speedup 1.0000x reference)
//
#include <hip/hip_runtime.h>
#include <math.h>

#define NBATCH 128
#define NTIME  256
#define NCH    512
#define NH     512
#define NSTEPS 32
#define NOUT   96
#define MTOT   32768
#define GRID_P 256

typedef __attribute__((ext_vector_type(8))) short short8v;
typedef __attribute__((ext_vector_type(4))) float f32x4;

typedef const __attribute__((address_space(1))) unsigned int g_as_uint;
typedef __attribute__((address_space(3))) unsigned int l_as_uint;

__device__ __forceinline__ void gl_lds16(const void* g, void* l) {
    __builtin_amdgcn_global_load_lds((g_as_uint*)g, (l_as_uint*)l, 16, 0, 0);
}

__device__ __forceinline__ float fast_tanh(float x) {
    x = fminf(fmaxf(x, -30.f), 30.f);
    float u = __expf(2.f * x);
    return (u - 1.f) / (u + 1.f);
}
__device__ __forceinline__ float fast_sigmoid(float x) {
    x = fminf(fmaxf(x, -30.f), 30.f);
    return 1.f / (1.f + __expf(-x));
}
__device__ __forceinline__ float wave_reduce_sum(float s) {
    #pragma unroll
    for (int off = 32; off; off >>= 1) s += __shfl_xor(s, off, 64);
    return s;
}
__device__ __forceinline__ float wave_reduce_max(float s) {
    #pragma unroll
    for (int off = 32; off; off >>= 1) s = fmaxf(s, __shfl_xor(s, off, 64));
    return s;
}
__device__ __forceinline__ unsigned short f2bf(float f) {
    unsigned u = __builtin_bit_cast(unsigned, f);
    return (unsigned short)((u + 0x7FFFu + ((u >> 16) & 1u)) >> 16);
}
__device__ __forceinline__ float bflo(unsigned u) {
    return __builtin_bit_cast(float, u << 16);
}
__device__ __forceinline__ float bfhi(unsigned u) {
    return __builtin_bit_cast(float, u & 0xFFFF0000u);
}

// ---- agent-scope (cross-XCD coherent) relaxed accessors: sc1 path, no fences
__device__ __forceinline__ float ld4f(const float* p) {
    return __hip_atomic_load(p, __ATOMIC_RELAXED, __HIP_MEMORY_SCOPE_AGENT);
}
__device__ __forceinline__ void st4f(float* p, float v) {
    __hip_atomic_store(p, v, __ATOMIC_RELAXED, __HIP_MEMORY_SCOPE_AGENT);
}
__device__ __forceinline__ float2 ld8f(const float* p) {
    unsigned long long u =
        __hip_atomic_load((const unsigned long long*)p, __ATOMIC_RELAXED, __HIP_MEMORY_SCOPE_AGENT);
    return __builtin_bit_cast(float2, u);
}
__device__ __forceinline__ void st8f(float* p, float x, float y) {
    float2 v = make_float2(x, y);
    __hip_atomic_store((unsigned long long*)p, __builtin_bit_cast(unsigned long long, v),
                       __ATOMIC_RELAXED, __HIP_MEMORY_SCOPE_AGENT);
}
__device__ __forceinline__ unsigned long long ld8u(const unsigned short* p) {
    return __hip_atomic_load((const unsigned long long*)p, __ATOMIC_RELAXED, __HIP_MEMORY_SCOPE_AGENT);
}
__device__ __forceinline__ void st2a(unsigned short* p, unsigned short v) {
    __hip_atomic_store(p, v, __ATOMIC_RELAXED, __HIP_MEMORY_SCOPE_AGENT);
}

// Device-wide barrier: relaxed monotonic counter. __syncthreads before arrive
// drains vmcnt (sc1 stores already at coherence point). NO fences/invalidate.
__device__ __forceinline__ void gbar2(int* cnt, int bar) {
    __syncthreads();
    if (threadIdx.x == 0) {
        __hip_atomic_fetch_add(cnt, 1, __ATOMIC_RELAXED, __HIP_MEMORY_SCOPE_AGENT);
        while (__hip_atomic_load(cnt, __ATOMIC_RELAXED, __HIP_MEMORY_SCOPE_AGENT)
               < bar * GRID_P)
            __builtin_amdgcn_s_sleep(1);
    }
    __syncthreads();
}

// ---------------------------------------------------------------------------
// Wi2h fp32 [512][512] -> bf16 same layout
__global__ __launch_bounds__(256) void k_w2bf(const float* __restrict__ W,
                                              unsigned short* __restrict__ Wb) {
    #pragma unroll
    for (int r = 0; r < 4; ++r) {
        int idx = (blockIdx.x * 256 + threadIdx.x) + r * 16384;
        float4 v = *(const float4*)(W + (size_t)idx * 4);
        ushort4 o;
        o.x = f2bf(v.x); o.y = f2bf(v.y); o.z = f2bf(v.z); o.w = f2bf(v.w);
        *(ushort4*)(Wb + (size_t)idx * 4) = o;
    }
}

// ---------------------------------------------------------------------------
// Wgb = concat(Wih, Whh) fp32 [3072][512] -> bf16
__global__ __launch_bounds__(256) void k_wg2bf(const float* __restrict__ Wih,
                                               const float* __restrict__ Whh,
                                               unsigned short* __restrict__ Wgb) {
    #pragma unroll
    for (int r = 0; r < 4; ++r) {
        int idx = (blockIdx.x * 256 + threadIdx.x) + r * 98304;
        const float* src = (idx < 196608) ? (Wih + (size_t)idx * 4)
                                          : (Whh + (size_t)(idx - 196608) * 4);
        float4 v = *(const float4*)src;
        ushort4 o;
        o.x = f2bf(v.x); o.y = f2bf(v.y); o.z = f2bf(v.z); o.w = f2bf(v.w);
        *(ushort4*)(Wgb + (size_t)idx * 4) = o;
    }
}

// ---------------------------------------------------------------------------
// FUSED feats prep (big-ws): one read of feats -> featsb (same layout bf16)
// AND Fb (transposed [m][k] bf16)
__global__ __launch_bounds__(256) void k_prep(const float* __restrict__ feats,
                                              unsigned short* __restrict__ featsb,
                                              unsigned short* __restrict__ Fb) {
    __shared__ float tl[64][65];
    const int m0 = (blockIdx.x & 511) * 64;
    const int k0 = (blockIdx.x >> 9) * 64;
    const int tid = threadIdx.x;
    #pragma unroll
    for (int p = 0; p < 4; ++p) {
        int fid = tid + p * 256;
        int row = fid >> 4, c4 = fid & 15;
        float4 v = *(const float4*)(feats + (size_t)(k0 + row) * MTOT + m0 + c4 * 4);
        tl[row][c4 * 4 + 0] = v.x; tl[row][c4 * 4 + 1] = v.y;
        tl[row][c4 * 4 + 2] = v.z; tl[row][c4 * 4 + 3] = v.w;
        ushort4 o;
        o.x = f2bf(v.x); o.y = f2bf(v.y); o.z = f2bf(v.z); o.w = f2bf(v.w);
        *(ushort4*)(featsb + (size_t)(k0 + row) * MTOT + m0 + c4 * 4) = o;
    }
    __syncthreads();
    #pragma unroll
    for (int p = 0; p < 4; ++p) {
        int cid = tid + p * 256;
        int mm = cid >> 4, ch = cid & 15;
        ushort4 o;
        o.x = f2bf(tl[ch * 4 + 0][mm]);
        o.y = f2bf(tl[ch * 4 + 1][mm]);
        o.z = f2bf(tl[ch * 4 + 2][mm]);
        o.w = f2bf(tl[ch * 4 + 3][mm]);
        *(ushort4*)(Fb + (size_t)(m0 + mm) * 512 + k0 + ch * 4) = o;
    }
}

// Fallback (small ws): transpose only
__global__ __launch_bounds__(256) void k_feats2bf(const float* __restrict__ feats,
                                                  unsigned short* __restrict__ Fb) {
    __shared__ float tl[64][65];
    const int m0 = (blockIdx.x & 511) * 64;
    const int k0 = (blockIdx.x >> 9) * 64;
    const int tid = threadIdx.x;
    #pragma unroll
    for (int p = 0; p < 4; ++p) {
        int fid = tid + p * 256;
        int row = fid >> 4, c4 = fid & 15;
        float4 v = *(const float4*)(feats + (size_t)(k0 + row) * MTOT + m0 + c4 * 4);
        tl[row][c4 * 4 + 0] = v.x; tl[row][c4 * 4 + 1] = v.y;
        tl[row][c4 * 4 + 2] = v.z; tl[row][c4 * 4 + 3] = v.w;
    }
    __syncthreads();
    #pragma unroll
    for (int p = 0; p < 4; ++p) {
        int cid = tid + p * 256;
        int mm = cid >> 4, ch = cid & 15;
        ushort4 o;
        o.x = f2bf(tl[ch * 4 + 0][mm]);
        o.y = f2bf(tl[ch * 4 + 1][mm]);
        o.z = f2bf(tl[ch * 4 + 2][mm]);
        o.w = f2bf(tl[ch * 4 + 3][mm]);
        *(ushort4*)(Fb + (size_t)(m0 + mm) * 512 + k0 + ch * 4) = o;
    }
}

__global__ __launch_bounds__(1024) void k_fcopy(const float* __restrict__ f,
                                                unsigned short* __restrict__ o) {
    int gid = blockIdx.x * 1024 + threadIdx.x;
    float4 v = *(const float4*)(f + (size_t)gid * 4);
    ushort4 s;
    s.x = f2bf(v.x); s.y = f2bf(v.y); s.z = f2bf(v.z); s.w = f2bf(v.w);
    *(ushort4*)(o + (size_t)gid * 4) = s;
}

// ---------------------------------------------------------------------------
// MFMA GEMM: fp[m][h] (bf16 out) — unchanged from round 10
__global__ __launch_bounds__(256) void k_fp_mfma(const unsigned short* __restrict__ Wb,
                                                 const unsigned short* __restrict__ Fb,
                                                 unsigned short* __restrict__ fp_bf) {
    __shared__ char SB[49152];
    unsigned short* As = (unsigned short*)SB;
    unsigned short* Bs = (unsigned short*)(SB + 16384);
    float* tl = (float*)SB;
    const int m0 = (blockIdx.x & 127) * 256;
    const int h0 = (blockIdx.x >> 7) * 128;
    const int tid = threadIdx.x;
    const int lane = tid & 63;
    const int wid = __builtin_amdgcn_readfirstlane(tid >> 6);
    const int wh = wid & 1, wm = wid >> 1;
    const int l8 = lane >> 3, c8 = lane & 7;
    f32x4 acc[4][8];
    #pragma unroll
    for (int i = 0; i < 4; ++i)
        #pragma unroll
        for (int j = 0; j < 8; ++j) acc[i][j] = (f32x4)0.f;

    for (int k0 = 0; k0 < 512; k0 += 64) {
        #pragma unroll
        for (int i = 0; i < 4; ++i) {
            int slot = wid * 4 + i;
            int row = slot * 8 + l8;
            gl_lds16(Wb + (size_t)(h0 + row) * 512 + k0 + ((c8 ^ (row & 7)) << 3),
                     As + slot * 512);
        }
        #pragma unroll
        for (int i = 0; i < 8; ++i) {
            int slot = wid * 8 + i;
            int row = slot * 8 + l8;
            gl_lds16(Fb + (size_t)(m0 + row) * 512 + k0 + ((c8 ^ (row & 7)) << 3),
                     Bs + slot * 512);
        }
        __syncthreads();
        #pragma unroll
        for (int ks = 0; ks < 2; ++ks) {
            short8v a[4], b[8];
            #pragma unroll
            for (int hf = 0; hf < 4; ++hf) {
                int row = wh * 64 + hf * 16 + (lane & 15);
                int ch = ks * 4 + (lane >> 4);
                a[hf] = *(const short8v*)(As + row * 64 + ((ch ^ (row & 7)) << 3));
            }
            #pragma unroll
            for (int mf = 0; mf < 8; ++mf) {
                int row = wm * 128 + mf * 16 + (lane & 15);
                int ch = ks * 4 + (lane >> 4);
                b[mf] = *(const short8v*)(Bs + row * 64 + ((ch ^ (row & 7)) << 3));
            }
            #pragma unroll
            for (int hf = 0; hf < 4; ++hf)
                #pragma unroll
                for (int mf = 0; mf < 8; ++mf)
                    acc[hf][mf] = __builtin_amdgcn_mfma_f32_16x16x32_bf16(
                        a[hf], b[mf], acc[hf][mf], 0, 0, 0);
        }
        __syncthreads();
    }
    #pragma unroll
    for (int hf = 0; hf < 4; ++hf) {
        #pragma unroll
        for (int mf = 0; mf < 8; ++mf) {
            int ml = wm * 128 + mf * 16 + (lane & 15);
            int col = wh * 16 + (lane >> 4) * 4;
            tl[ml * 33 + col + 0] = acc[hf][mf][0];
            tl[ml * 33 + col + 1] = acc[hf][mf][1];
            tl[ml * 33 + col + 2] = acc[hf][mf][2];
            tl[ml * 33 + col + 3] = acc[hf][mf][3];
        }
        __syncthreads();
        #pragma unroll
        for (int mi = 0; mi < 8; ++mi) {
            int ml = (tid >> 3) + mi * 32;
            int hl4 = (tid & 7) * 4;
            float v0 = tl[ml * 33 + hl4 + 0];
            float v1 = tl[ml * 33 + hl4 + 1];
            float v2 = tl[ml * 33 + hl4 + 2];
            float v3 = tl[ml * 33 + hl4 + 3];
            int hg = h0 + ((hl4 < 16) ? (hf * 16 + hl4) : (64 + hf * 16 + hl4 - 16));
            ushort4 o;
            o.x = f2bf(v0); o.y = f2bf(v1); o.z = f2bf(v2); o.w = f2bf(v3);
            *(ushort4*)(fp_bf + (size_t)(m0 + ml) * 512 + hg) = o;
        }
        __syncthreads();
    }
}

// ---------------------------------------------------------------------------
// Transpose Wh2h -> WTb[k][j] bf16
__global__ __launch_bounds__(256) void k_wt(const float* __restrict__ W,
                                            unsigned short* __restrict__ WTb) {
    __shared__ float tl[32][33];
    const int bi = blockIdx.x & 15, bj = blockIdx.x >> 4;
    const int tx = threadIdx.x & 31, ty8 = threadIdx.x >> 5;
    #pragma unroll
    for (int i = 0; i < 4; ++i) {
        int r = ty8 * 4 + i;
        tl[r][tx] = W[(size_t)(bj * 32 + r) * NH + bi * 32 + tx];
    }
    __syncthreads();
    #pragma unroll
    for (int i = 0; i < 4; ++i) {
        int c = ty8 * 4 + i;
        WTb[(size_t)(bi * 32 + c) * NH + bj * 32 + tx] = f2bf(tl[tx][c]);
    }
}

// ---------------------------------------------------------------------------
// Persistent decode loop. 256 blocks x 1024 threads, 96KB LDS (1 block/CU,
// all co-resident). Read-only streams (fp_bf, featsb, weights) use normal
// cached loads; cross-phase buffers use agent-scope relaxed atomics (sc1).
__global__ __launch_bounds__(1024) void k_loop2(
    const unsigned short* __restrict__ fp_bf,
    const unsigned short* __restrict__ featsb,
    const float* __restrict__ wscore,
    const unsigned short* __restrict__ Wgb,
    const float* __restrict__ bih,
    const float* __restrict__ bhh,
    const unsigned short* __restrict__ WTb,
    const float* __restrict__ bh2h,
    float* hid,
    float* hp,
    unsigned short* ctx_bf,
    unsigned short* h_bf,
    float* e,
    float* g2,
    int* cnt)
{
    __shared__ float POOL[24576];      // 96 KB
    const int blk = blockIdx.x;
    const int tid = threadIdx.x;
    const int lane = tid & 63, w = tid >> 6;
    int bar = 0;

    // P0: hp = bh2h broadcast; hid[0] = 0; h_bf = 0
    {
        int idx = blk * 256 + tid;      // 256*1024 = 262144 >= 65536
        if (idx < 65536) {
            st4f(hp + idx, bh2h[idx & 511]);
            st4f(hid + idx, 0.f);
            st2a(h_bf + idx, (unsigned short)0);
        }
    }
    gbar2(cnt, ++bar);

    for (int s = 0; s < NSTEPS; ++s) {
        const float* hprev = hid + (size_t)s * 65536;
        float* hnext      = hid + (size_t)(s + 1) * 65536;

        // ---- P1: e[b][t] = sum_h tanh(fp+hp)*wscore ----
        {
            const int b = blk >> 1;
            const int tbase = (blk & 1) * 128 + w * 8;
            const float* hpb = hp + (size_t)b * NH + lane * 8;
            float2 ha = ld8f(hpb), hb = ld8f(hpb + 2), hc = ld8f(hpb + 4), hd = ld8f(hpb + 6);
            float4 w0 = *(const float4*)(wscore + lane * 8);
            float4 w1 = *(const float4*)(wscore + lane * 8 + 4);
            #pragma unroll
            for (int it = 0; it < 8; ++it) {
                int t = tbase + it;
                uint4 v = *(const uint4*)(fp_bf + (size_t)(b * NTIME + t) * NH + lane * 8);
                float sv =
                    fast_tanh(bflo(v.x) + ha.x) * w0.x + fast_tanh(bfhi(v.x) + ha.y) * w0.y +
                    fast_tanh(bflo(v.y) + hb.x) * w0.z + fast_tanh(bfhi(v.y) + hb.y) * w0.w +
                    fast_tanh(bflo(v.z) + hc.x) * w1.x + fast_tanh(bfhi(v.z) + hc.y) * w1.y +
                    fast_tanh(bflo(v.w) + hd.x) * w1.z + fast_tanh(bfhi(v.w) + hd.y) * w1.w;
                sv = wave_reduce_sum(sv);
                if (lane == 0) st4f(e + b * NTIME + t, sv);
            }
        }
        gbar2(cnt, ++bar);

        // ---- P2: softmax + ctx ----
        {
            float* als = POOL;
            float* red = POOL + 256;
            const int b = blk >> 1;
            const int c0 = (blk & 1) * 256;
            float v = (tid < 256) ? ld4f(e + b * NTIME + tid) : -3.4e38f;
            float m = wave_reduce_max(v);
            if (lane == 0) red[w] = m;
            __syncthreads();
            m = red[0];
            #pragma unroll
            for (int i = 1; i < 16; ++i) m = fmaxf(m, red[i]);
            float ex = (tid < 256) ? __expf(v - m) : 0.f;
            float sm = wave_reduce_sum(ex);
            __syncthreads();
            if (lane == 0) red[w] = sm;
            __syncthreads();
            sm = 0.f;
            #pragma unroll
            for (int i = 0; i < 16; ++i) sm += red[i];
            __syncthreads();
            if (tid < 256) als[tid] = ex / sm;
            __syncthreads();
            float4 al = *(const float4*)&als[lane * 4];
            #pragma unroll
            for (int cc = 0; cc < 16; ++cc) {
                int c = c0 + w * 16 + cc;
                uint2 fv = *(const uint2*)(featsb + (size_t)(c * NBATCH + b) * NTIME + lane * 4);
                float sc = bflo(fv.x) * al.x + bfhi(fv.x) * al.y +
                           bflo(fv.y) * al.z + bfhi(fv.y) * al.w;
                sc = wave_reduce_sum(sc);
                if (lane == 0) st2a(ctx_bf + (size_t)b * NCH + c, f2bf(sc));
            }
        }
        gbar2(cnt, ++bar);

        // ---- P3: gates GEMM (blocks 0..23 active; weights cached, A via sc1) ----
        {
            const bool blkact = (blk < 24);
            const bool act = blkact && (tid < 256);
            const int j0 = blk * 128;
            const unsigned short* Aact = (j0 < 1536) ? ctx_bf : h_bf;
            unsigned short* AsU = (unsigned short*)POOL;
            unsigned short* BsU = AsU + 8192;
            const int wid4 = tid >> 6;
            const int wb = wid4 & 1, wj = wid4 >> 1;
            const int l8 = lane >> 3, c8 = lane & 7;
            f32x4 acc[4][4];
            #pragma unroll
            for (int i = 0; i < 4; ++i)
                #pragma unroll
                for (int j = 0; j < 4; ++j) acc[i][j] = (f32x4)0.f;

            for (int k0 = 0; k0 < 512; k0 += 64) {
                if (act) {
                    #pragma unroll
                    for (int i = 0; i < 4; ++i) {
                        int cid = tid + i * 256;
                        int row = cid >> 3, ch = cid & 7;
                        const unsigned short* src = Aact + (size_t)row * 512 + k0 + ch * 8;
                        unsigned long long lo = ld8u(src);
                        unsigned long long hi = ld8u(src + 4);
                        unsigned short* dst = AsU + row * 64 + ((ch ^ (row & 7)) << 3);
                        *(unsigned long long*)(dst)     = lo;
                        *(unsigned long long*)(dst + 4) = hi;
                        int slot = wid4 * 4 + i;
                        int rowb = slot * 8 + l8;
                        gl_lds16(Wgb + (size_t)(j0 + rowb) * 512 + k0 + ((c8 ^ (rowb & 7)) << 3),
                                 BsU + slot * 512);
                    }
                }
                __syncthreads();
                if (act) {
                    #pragma unroll
                    for (int ks = 0; ks < 2; ++ks) {
                        short8v a[4], b[4];
                        #pragma unroll
                        for (int f = 0; f < 4; ++f) {
                            int rowa = wb * 64 + f * 16 + (lane & 15);
                            int rowb = wj * 64 + f * 16 + (lane & 15);
                            int ch = ks * 4 + (lane >> 4);
                            a[f] = *(const short8v*)(AsU + rowa * 64 + ((ch ^ (rowa & 7)) << 3));
                            b[f] = *(const short8v*)(BsU + rowb * 64 + ((ch ^ (rowb & 7)) << 3));
                        }
                        #pragma unroll
                        for (int bf = 0; bf < 4; ++bf)
                            #pragma unroll
                            for (int jf = 0; jf < 4; ++jf)
                                acc[bf][jf] = __builtin_amdgcn_mfma_f32_16x16x32_bf16(
                                    a[bf], b[jf], acc[bf][jf], 0, 0, 0);
                    }
                }
                __syncthreads();
            }
            if (act) {
                #pragma unroll
                for (int bf = 0; bf < 4; ++bf) {
                    int b = wb * 64 + bf * 16 + (lane >> 4) * 4;
                    #pragma unroll
                    for (int jf = 0; jf < 4; ++jf) {
                        int j = j0 + wj * 64 + jf * 16 + (lane & 15);
                        st8f(g2 + (size_t)j * NBATCH + b,     acc[bf][jf][0], acc[bf][jf][1]);
                        st8f(g2 + (size_t)j * NBATCH + b + 2, acc[bf][jf][2], acc[bf][jf][3]);
                    }
                }
            }
        }
        gbar2(cnt, ++bar);

        // ---- P4: GRU combine -> hnext/h_bf; hp_next GEMV ----
        {
            float* h_s  = POOL;          // 2048
            float* scr2 = POOL + 2048;   // 4096
            const int b0 = (blk >> 3) * 4;
            const int jbase = (blk & 7) * 64;
            #pragma unroll
            for (int rep = 0; rep < 2; ++rep) {
                int idx = tid + rep * 1024;
                int bi = idx & 3, kk = idx >> 2;
                int b = b0 + bi;
                float ir  = ld4f(g2 + (size_t)(0 * 512 + kk) * NBATCH + b) + bih[kk];
                float iz  = ld4f(g2 + (size_t)(1 * 512 + kk) * NBATCH + b) + bih[512 + kk];
                float in_ = ld4f(g2 + (size_t)(2 * 512 + kk) * NBATCH + b) + bih[1024 + kk];
                float hr  = ld4f(g2 + (size_t)(3 * 512 + kk) * NBATCH + b) + bhh[kk];
                float hz  = ld4f(g2 + (size_t)(4 * 512 + kk) * NBATCH + b) + bhh[512 + kk];
                float hn  = ld4f(g2 + (size_t)(5 * 512 + kk) * NBATCH + b) + bhh[1024 + kk];
                float r = fast_sigmoid(ir + hr);
                float z = fast_sigmoid(iz + hz);
                float ng = fast_tanh(in_ + r * hn);
                float hv = ld4f(hprev + (size_t)b * NH + kk);
                float hnew = (1.f - z) * ng + z * hv;
                h_s[bi * 512 + kk] = hnew;
                if ((blk & 7) == 0) {
                    st4f(hnext + (size_t)b * NH + kk, hnew);
                    st2a(h_bf + (size_t)b * NH + kk, f2bf(hnew));
                }
            }
            __syncthreads();
            {
                const int jq = tid & 15, bi = (tid >> 4) & 3, kq = tid >> 6;
                const int j = jbase + jq * 4;
                float4 acc4 = make_float4(0.f, 0.f, 0.f, 0.f);
                #pragma unroll 8
                for (int kk = 0; kk < 32; ++kk) {
                    int k = kq * 32 + kk;
                    uint2 wq = *(const uint2*)(WTb + (size_t)k * NH + j);
                    float hv = h_s[bi * 512 + k];
                    acc4.x += hv * bflo(wq.x); acc4.y += hv * bfhi(wq.x);
                    acc4.z += hv * bflo(wq.y); acc4.w += hv * bfhi(wq.y);
                }
                *(float4*)&scr2[((kq * 4 + bi) * 16 + jq) * 4] = acc4;
            }
            __syncthreads();
            if (tid < 64) {
                const int bi = tid >> 4, jq = tid & 15;
                float4 sum = make_float4(0.f, 0.f, 0.f, 0.f);
                #pragma unroll
                for (int kq = 0; kq < 16; ++kq) {
                    float4 p = *(const float4*)&scr2[((kq * 4 + bi) * 16 + jq) * 4];
                    sum.x += p.x; sum.y += p.y; sum.z += p.z; sum.w += p.w;
                }
                int j = jbase + jq * 4;
                float4 bb = *(const float4*)(bh2h + j);
                st8f(hp + (size_t)(b0 + bi) * NH + j,     sum.x + bb.x, sum.y + bb.y);
                st8f(hp + (size_t)(b0 + bi) * NH + j + 2, sum.z + bb.z, sum.w + bb.w);
            }
            __syncthreads();
        }
        if (s < NSTEPS - 1) gbar2(cnt, ++bar);
    }
}

// ---------------------------------------------------------------------------
__global__ __launch_bounds__(256) void k_gen(const float* __restrict__ hid,
                                             const float* __restrict__ Wgen,
                                             const float* __restrict__ bgen,
                                             float* __restrict__ out) {
    __shared__ float As[32][36];
    __shared__ float Bs[32][97];
    const int m0 = blockIdx.x * 32;
    const int tid = threadIdx.x;
    const int tx = tid & 31, ty = tid >> 5;
    float acc[4][3] = {};
    for (int k0 = 0; k0 < 512; k0 += 32) {
        {
            int mm = tid >> 3, kq = (tid & 7) << 2;
            int m = m0 + mm, s = m & 31, b = m >> 5;
            float4 v = *(const float4*)(hid + (size_t)(s + 1) * 65536 + b * 512 + k0 + kq);
            *(float4*)(&As[mm][kq]) = v;
        }
        #pragma unroll
        for (int i = 0; i < 3; ++i) {
            int f4 = tid + i * 256;
            int nn = f4 >> 3, kq = (f4 & 7) << 2;
            float4 v = *(const float4*)(Wgen + (size_t)nn * 512 + k0 + kq);
            Bs[kq + 0][nn] = v.x; Bs[kq + 1][nn] = v.y;
            Bs[kq + 2][nn] = v.z; Bs[kq + 3][nn] = v.w;
        }
        __syncthreads();
        #pragma unroll
        for (int kk = 0; kk < 32; ++kk) {
            float bv[3];
            #pragma unroll
            for (int j = 0; j < 3; ++j) bv[j] = Bs[kk][tx * 3 + j];
            #pragma unroll
            for (int i = 0; i < 4; ++i) {
                float a = As[ty * 4 + i][kk];
                #pragma unroll
                for (int j = 0; j < 3; ++j) acc[i][j] += a * bv[j];
            }
        }
        __syncthreads();
    }
    #pragma unroll
    for (int i = 0; i < 4; ++i)
        #pragma unroll
        for (int j = 0; j < 3; ++j)
            out[(size_t)(m0 + ty * 4 + i) * NOUT + tx * 3 + j] = acc[i][j] + bgen[tx * 3 + j];
}

// ---------------------------------------------------------------------------
extern "C" void kernel_launch(void* const* d_in, const int* in_sizes, int n_in,
                              void* d_out, int out_size, void* d_ws, size_t ws_size,
                              hipStream_t stream) {
    const float* feats  = (const float*)d_in[0];
    const float* Wi2h   = (const float*)d_in[2];
    const float* Wh2h   = (const float*)d_in[3];
    const float* bh2h   = (const float*)d_in[4];
    const float* Wscore = (const float*)d_in[5];
    const float* Wih    = (const float*)d_in[6];
    const float* Whh    = (const float*)d_in[7];
    const float* bih    = (const float*)d_in[8];
    const float* bhh    = (const float*)d_in[9];
    const float* Wgen   = (const float*)d_in[10];
    const float* bgen   = (const float*)d_in[11];
    float* out = (float*)d_out;

    // ws layout (float-slot offsets):
    float* ws  = (float*)d_ws;
    unsigned short* fp_bf  = (unsigned short*)ws;                     // 16,777,216 bf16
    float*          hid    = ws + 8388608;                            // 2,162,688 f32
    float*          hp     = hid + 2162688;                           // 65,536 f32
    unsigned short* ctx_bf = (unsigned short*)(hp + 65536);           // 65,536 bf16
    unsigned short* h_bf   = (unsigned short*)(hp + 65536 + 32768);   // 65,536 bf16
    unsigned short* WTb    = (unsigned short*)(hp + 65536 + 65536);   // 262,144 bf16
    unsigned short* Wgb    = (unsigned short*)(hp + 65536 + 65536 + 131072);            // 1,572,864 bf16
    unsigned short* Wb     = (unsigned short*)(hp + 65536 + 65536 + 131072 + 786432);   // 262,144 bf16
    int*            cnt    = (int*)(hp + 65536 + 65536 + 131072 + 786432 + 131072);     // 16 f32 pad
    unsigned short* Fb     = (unsigned short*)(hp + 65536 + 65536 + 131072 + 786432 + 131072 + 16);
    const size_t base_floats = 8388608 + 2162688 + 65536 + 32768 + 32768 + 131072
                             + 786432 + 131072 + 16 + 8388608;
    const bool big = ws_size >= (base_floats + 8388608) * sizeof(float);
    unsigned short* featsb = big ? (Fb + 16777216) : Fb;

    float* e  = out;                // aliases g2 head; disjoint lifetimes
    float* g2 = out;                // 6*512*128 = 393216 = out_size

    hipMemsetAsync(cnt, 0, 16, stream);
    k_wt<<<256, 256, 0, stream>>>(Wh2h, WTb);
    k_w2bf<<<64, 256, 0, stream>>>(Wi2h, Wb);
    k_wg2bf<<<384, 256, 0, stream>>>(Wih, Whh, Wgb);
    if (big) {
        k_prep<<<4096, 256, 0, stream>>>(feats, featsb, Fb);
        k_fp_mfma<<<512, 256, 0, stream>>>(Wb, Fb, fp_bf);
    } else {
        k_feats2bf<<<4096, 256, 0, stream>>>(feats, Fb);
        k_fp_mfma<<<512, 256, 0, stream>>>(Wb, Fb, fp_bf);
        k_fcopy<<<4096, 1024, 0, stream>>>(feats, featsb);
    }

    k_loop2<<<GRID_P, 1024, 0, stream>>>(fp_bf, featsb, Wscore, Wgb, bih, bhh,
                                         WTb, bh2h, hid, hp, ctx_bf, h_bf,
                                         e, g2, cnt);

    k_gen<<<128, 256, 0, stream>>>(hid, Wgen, bgen, out);
}

// Round 12
// 1790.875 us; speedup vs baseline: 2.4992x; 2.4992x over previous
//
#include <hip/hip_runtime.h>
#include <math.h>

#define NBATCH 128
#define NTIME  256
#define NCH    512
#define NH     512
#define NSTEPS 32
#define NOUT   96
#define MTOT   32768

typedef __attribute__((ext_vector_type(8))) short short8v;
typedef __attribute__((ext_vector_type(4))) float f32x4;

typedef const __attribute__((address_space(1))) unsigned int g_as_uint;
typedef __attribute__((address_space(3))) unsigned int l_as_uint;

__device__ __forceinline__ void gl_lds16(const void* g, void* l) {
    __builtin_amdgcn_global_load_lds((g_as_uint*)g, (l_as_uint*)l, 16, 0, 0);
}

__device__ __forceinline__ float fast_tanh(float x) {
    x = fminf(fmaxf(x, -30.f), 30.f);
    float u = __expf(2.f * x);
    return (u - 1.f) / (u + 1.f);
}
__device__ __forceinline__ float fast_sigmoid(float x) {
    x = fminf(fmaxf(x, -30.f), 30.f);
    return 1.f / (1.f + __expf(-x));
}
__device__ __forceinline__ float wave_reduce_sum(float s) {
    #pragma unroll
    for (int off = 32; off; off >>= 1) s += __shfl_xor(s, off, 64);
    return s;
}
__device__ __forceinline__ unsigned short f2bf(float f) {
    unsigned u = __builtin_bit_cast(unsigned, f);
    return (unsigned short)((u + 0x7FFFu + ((u >> 16) & 1u)) >> 16);
}
__device__ __forceinline__ unsigned pk2bf(float a, float b) {
    return (unsigned)f2bf(a) | ((unsigned)f2bf(b) << 16);
}
__device__ __forceinline__ float bflo(unsigned u) {
    return __builtin_bit_cast(float, u << 16);
}
__device__ __forceinline__ float bfhi(unsigned u) {
    return __builtin_bit_cast(float, u & 0xFFFF0000u);
}

// ---------------------------------------------------------------------------
// Wi2h fp32 [512][512] -> bf16 same layout
__global__ __launch_bounds__(256) void k_w2bf(const float* __restrict__ W,
                                              unsigned short* __restrict__ Wb) {
    #pragma unroll
    for (int r = 0; r < 4; ++r) {
        int idx = (blockIdx.x * 256 + threadIdx.x) + r * 16384;
        float4 v = *(const float4*)(W + (size_t)idx * 4);
        ushort4 o;
        o.x = f2bf(v.x); o.y = f2bf(v.y); o.z = f2bf(v.z); o.w = f2bf(v.w);
        *(ushort4*)(Wb + (size_t)idx * 4) = o;
    }
}

// ---------------------------------------------------------------------------
// Wgb = concat(Wih, Whh) fp32 [3072][512] -> bf16
__global__ __launch_bounds__(256) void k_wg2bf(const float* __restrict__ Wih,
                                               const float* __restrict__ Whh,
                                               unsigned short* __restrict__ Wgb) {
    #pragma unroll
    for (int r = 0; r < 4; ++r) {
        int idx = (blockIdx.x * 256 + threadIdx.x) + r * 98304;
        const float* src = (idx < 196608) ? (Wih + (size_t)idx * 4)
                                          : (Whh + (size_t)(idx - 196608) * 4);
        float4 v = *(const float4*)src;
        ushort4 o;
        o.x = f2bf(v.x); o.y = f2bf(v.y); o.z = f2bf(v.z); o.w = f2bf(v.w);
        *(ushort4*)(Wgb + (size_t)idx * 4) = o;
    }
}

// ---------------------------------------------------------------------------
// FUSED feats prep (big-ws): one read of feats -> featsb (bf16 same layout)
// AND Fb (bf16 transposed [m][k])
__global__ __launch_bounds__(256) void k_prep(const float* __restrict__ feats,
                                              unsigned short* __restrict__ featsb,
                                              unsigned short* __restrict__ Fb) {
    __shared__ float tl[64][65];
    const int m0 = (blockIdx.x & 511) * 64;
    const int k0 = (blockIdx.x >> 9) * 64;
    const int tid = threadIdx.x;
    #pragma unroll
    for (int p = 0; p < 4; ++p) {
        int fid = tid + p * 256;
        int row = fid >> 4, c4 = fid & 15;
        float4 v = *(const float4*)(feats + (size_t)(k0 + row) * MTOT + m0 + c4 * 4);
        tl[row][c4 * 4 + 0] = v.x; tl[row][c4 * 4 + 1] = v.y;
        tl[row][c4 * 4 + 2] = v.z; tl[row][c4 * 4 + 3] = v.w;
        ushort4 o;
        o.x = f2bf(v.x); o.y = f2bf(v.y); o.z = f2bf(v.z); o.w = f2bf(v.w);
        *(ushort4*)(featsb + (size_t)(k0 + row) * MTOT + m0 + c4 * 4) = o;
    }
    __syncthreads();
    #pragma unroll
    for (int p = 0; p < 4; ++p) {
        int cid = tid + p * 256;
        int mm = cid >> 4, ch = cid & 15;
        ushort4 o;
        o.x = f2bf(tl[ch * 4 + 0][mm]);
        o.y = f2bf(tl[ch * 4 + 1][mm]);
        o.z = f2bf(tl[ch * 4 + 2][mm]);
        o.w = f2bf(tl[ch * 4 + 3][mm]);
        *(ushort4*)(Fb + (size_t)(m0 + mm) * 512 + k0 + ch * 4) = o;
    }
}

// Fallback (small ws): transpose only
__global__ __launch_bounds__(256) void k_feats2bf(const float* __restrict__ feats,
                                                  unsigned short* __restrict__ Fb) {
    __shared__ float tl[64][65];
    const int m0 = (blockIdx.x & 511) * 64;
    const int k0 = (blockIdx.x >> 9) * 64;
    const int tid = threadIdx.x;
    #pragma unroll
    for (int p = 0; p < 4; ++p) {
        int fid = tid + p * 256;
        int row = fid >> 4, c4 = fid & 15;
        float4 v = *(const float4*)(feats + (size_t)(k0 + row) * MTOT + m0 + c4 * 4);
        tl[row][c4 * 4 + 0] = v.x; tl[row][c4 * 4 + 1] = v.y;
        tl[row][c4 * 4 + 2] = v.z; tl[row][c4 * 4 + 3] = v.w;
    }
    __syncthreads();
    #pragma unroll
    for (int p = 0; p < 4; ++p) {
        int cid = tid + p * 256;
        int mm = cid >> 4, ch = cid & 15;
        ushort4 o;
        o.x = f2bf(tl[ch * 4 + 0][mm]);
        o.y = f2bf(tl[ch * 4 + 1][mm]);
        o.z = f2bf(tl[ch * 4 + 2][mm]);
        o.w = f2bf(tl[ch * 4 + 3][mm]);
        *(ushort4*)(Fb + (size_t)(m0 + mm) * 512 + k0 + ch * 4) = o;
    }
}

__global__ __launch_bounds__(1024) void k_fcopy(const float* __restrict__ f,
                                                unsigned short* __restrict__ o) {
    int gid = blockIdx.x * 1024 + threadIdx.x;
    float4 v = *(const float4*)(f + (size_t)gid * 4);
    ushort4 s;
    s.x = f2bf(v.x); s.y = f2bf(v.y); s.z = f2bf(v.z); s.w = f2bf(v.w);
    *(ushort4*)(o + (size_t)gid * 4) = s;
}

// ---------------------------------------------------------------------------
// MFMA GEMM: fp[m][h] (bf16 in/out) — unchanged from round 10
__global__ __launch_bounds__(256) void k_fp_mfma(const unsigned short* __restrict__ Wb,
                                                 const unsigned short* __restrict__ Fb,
                                                 unsigned short* __restrict__ fp_bf) {
    __shared__ char SB[49152];
    unsigned short* As = (unsigned short*)SB;
    unsigned short* Bs = (unsigned short*)(SB + 16384);
    float* tl = (float*)SB;
    const int m0 = (blockIdx.x & 127) * 256;
    const int h0 = (blockIdx.x >> 7) * 128;
    const int tid = threadIdx.x;
    const int lane = tid & 63;
    const int wid = __builtin_amdgcn_readfirstlane(tid >> 6);
    const int wh = wid & 1, wm = wid >> 1;
    const int l8 = lane >> 3, c8 = lane & 7;
    f32x4 acc[4][8];
    #pragma unroll
    for (int i = 0; i < 4; ++i)
        #pragma unroll
        for (int j = 0; j < 8; ++j) acc[i][j] = (f32x4)0.f;

    for (int k0 = 0; k0 < 512; k0 += 64) {
        #pragma unroll
        for (int i = 0; i < 4; ++i) {
            int slot = wid * 4 + i;
            int row = slot * 8 + l8;
            gl_lds16(Wb + (size_t)(h0 + row) * 512 + k0 + ((c8 ^ (row & 7)) << 3),
                     As + slot * 512);
        }
        #pragma unroll
        for (int i = 0; i < 8; ++i) {
            int slot = wid * 8 + i;
            int row = slot * 8 + l8;
            gl_lds16(Fb + (size_t)(m0 + row) * 512 + k0 + ((c8 ^ (row & 7)) << 3),
                     Bs + slot * 512);
        }
        __syncthreads();
        #pragma unroll
        for (int ks = 0; ks < 2; ++ks) {
            short8v a[4], b[8];
            #pragma unroll
            for (int hf = 0; hf < 4; ++hf) {
                int row = wh * 64 + hf * 16 + (lane & 15);
                int ch = ks * 4 + (lane >> 4);
                a[hf] = *(const short8v*)(As + row * 64 + ((ch ^ (row & 7)) << 3));
            }
            #pragma unroll
            for (int mf = 0; mf < 8; ++mf) {
                int row = wm * 128 + mf * 16 + (lane & 15);
                int ch = ks * 4 + (lane >> 4);
                b[mf] = *(const short8v*)(Bs + row * 64 + ((ch ^ (row & 7)) << 3));
            }
            #pragma unroll
            for (int hf = 0; hf < 4; ++hf)
                #pragma unroll
                for (int mf = 0; mf < 8; ++mf)
                    acc[hf][mf] = __builtin_amdgcn_mfma_f32_16x16x32_bf16(
                        a[hf], b[mf], acc[hf][mf], 0, 0, 0);
        }
        __syncthreads();
    }
    #pragma unroll
    for (int hf = 0; hf < 4; ++hf) {
        #pragma unroll
        for (int mf = 0; mf < 8; ++mf) {
            int ml = wm * 128 + mf * 16 + (lane & 15);
            int col = wh * 16 + (lane >> 4) * 4;
            tl[ml * 33 + col + 0] = acc[hf][mf][0];
            tl[ml * 33 + col + 1] = acc[hf][mf][1];
            tl[ml * 33 + col + 2] = acc[hf][mf][2];
            tl[ml * 33 + col + 3] = acc[hf][mf][3];
        }
        __syncthreads();
        #pragma unroll
        for (int mi = 0; mi < 8; ++mi) {
            int ml = (tid >> 3) + mi * 32;
            int hl4 = (tid & 7) * 4;
            float v0 = tl[ml * 33 + hl4 + 0];
            float v1 = tl[ml * 33 + hl4 + 1];
            float v2 = tl[ml * 33 + hl4 + 2];
            float v3 = tl[ml * 33 + hl4 + 3];
            int hg = h0 + ((hl4 < 16) ? (hf * 16 + hl4) : (64 + hf * 16 + hl4 - 16));
            ushort4 o;
            o.x = f2bf(v0); o.y = f2bf(v1); o.z = f2bf(v2); o.w = f2bf(v3);
            *(ushort4*)(fp_bf + (size_t)(m0 + ml) * 512 + hg) = o;
        }
        __syncthreads();
    }
}

// ---------------------------------------------------------------------------
// Transpose Wh2h -> WTb[k][j] bf16
__global__ __launch_bounds__(256) void k_wt(const float* __restrict__ W,
                                            unsigned short* __restrict__ WTb) {
    __shared__ float tl[32][33];
    const int bi = blockIdx.x & 15, bj = blockIdx.x >> 4;
    const int tx = threadIdx.x & 31, ty8 = threadIdx.x >> 5;
    #pragma unroll
    for (int i = 0; i < 4; ++i) {
        int r = ty8 * 4 + i;
        tl[r][tx] = W[(size_t)(bj * 32 + r) * NH + bi * 32 + tx];
    }
    __syncthreads();
    #pragma unroll
    for (int i = 0; i < 4; ++i) {
        int c = ty8 * 4 + i;
        WTb[(size_t)(bi * 32 + c) * NH + bj * 32 + tx] = f2bf(tl[tx][c]);
    }
}

// ---------------------------------------------------------------------------
// Init: hp = bh2h; zero both ctx_un bufs + esum bufs; C = ||wscore||_1 (block 0)
__global__ __launch_bounds__(1024) void k_init(const float* __restrict__ bh2h,
                                               const float* __restrict__ wscore,
                                               float* __restrict__ hp,
                                               float* __restrict__ ctx_un,   // [2][65536]
                                               float* __restrict__ esum,     // [2][128]
                                               float* __restrict__ Cbuf) {
    __shared__ float cred[16];
    int idx = blockIdx.x * 1024 + threadIdx.x;      // 65536
    hp[idx] = bh2h[idx & 511];
    ctx_un[idx] = 0.f;
    ctx_un[idx + 65536] = 0.f;
    if (idx < 256) esum[idx] = 0.f;
    if (blockIdx.x == 0) {
        const int tid = threadIdx.x, lane = tid & 63, w = tid >> 6;
        float v = (tid < 512) ? fabsf(wscore[tid]) : 0.f;
        v = wave_reduce_sum(v);
        if (lane == 0) cred[w] = v;
        __syncthreads();
        if (tid == 0) {
            float c = 0.f;
            #pragma unroll
            for (int i = 0; i < 16; ++i) c += cred[i];
            Cbuf[0] = c;
        }
    }
}

// ---------------------------------------------------------------------------
// FUSED e + softmax(fixed offset C) + ctx accumulation.
// 1024 blocks x 512: block (b = blk>>3, t-range 32 = (blk&7)*32).
// eexp stays in LDS; ctx_un[b][c] += sum_t feats*eexp via device atomics;
// esum[b] += partial. Normalization (1/esum) deferred to GRU combine.
__global__ __launch_bounds__(512) void k_ectx(const unsigned short* __restrict__ fp_bf,
                                              const unsigned short* __restrict__ featsb,
                                              const float* __restrict__ hp,
                                              const float* __restrict__ wscore,
                                              const float* __restrict__ Cbuf,
                                              float* __restrict__ ctx_un,
                                              float* __restrict__ esum) {
    __shared__ float e_s[32];
    const int b = blockIdx.x >> 3;
    const int t0 = (blockIdx.x & 7) * 32;
    const int tid = threadIdx.x;
    const int lane = tid & 63, w = tid >> 6;
    const float C = Cbuf[0];

    // Phase A: eexp[t] for 32 t's (8 waves x 4 t), loads hoisted
    {
        float4 h0 = *(const float4*)(hp + (size_t)b * NH + lane * 8);
        float4 h1 = *(const float4*)(hp + (size_t)b * NH + lane * 8 + 4);
        float4 w0 = *(const float4*)(wscore + lane * 8);
        float4 w1 = *(const float4*)(wscore + lane * 8 + 4);
        const unsigned short* base = fp_bf + (size_t)(b * NTIME + t0 + w * 4) * NH + lane * 8;
        uint4 v0 = *(const uint4*)(base);
        uint4 v1 = *(const uint4*)(base + NH);
        uint4 v2 = *(const uint4*)(base + 2 * NH);
        uint4 v3 = *(const uint4*)(base + 3 * NH);
        uint4 vv[4] = {v0, v1, v2, v3};
        #pragma unroll
        for (int it = 0; it < 4; ++it) {
            uint4 v = vv[it];
            float sv =
                fast_tanh(bflo(v.x) + h0.x) * w0.x + fast_tanh(bfhi(v.x) + h0.y) * w0.y +
                fast_tanh(bflo(v.y) + h0.z) * w0.z + fast_tanh(bfhi(v.y) + h0.w) * w0.w +
                fast_tanh(bflo(v.z) + h1.x) * w1.x + fast_tanh(bfhi(v.z) + h1.y) * w1.y +
                fast_tanh(bflo(v.w) + h1.z) * w1.z + fast_tanh(bfhi(v.w) + h1.w) * w1.w;
            sv = wave_reduce_sum(sv);
            if (lane == 0) e_s[w * 4 + it] = __expf(sv - C);
        }
    }
    __syncthreads();

    // esum partial (one wave)
    if (tid < 64) {
        float v = (lane < 32) ? e_s[lane] : 0.f;
        v = wave_reduce_sum(v);
        if (lane == 0) atomicAdd(esum + b, v);
    }

    // Phase B: thread owns c = tid; 32-t dot with eexp (broadcast from LDS)
    float er[32];
    #pragma unroll
    for (int i = 0; i < 8; ++i) {
        float4 q = *(const float4*)&e_s[i * 4];
        er[i * 4 + 0] = q.x; er[i * 4 + 1] = q.y;
        er[i * 4 + 2] = q.z; er[i * 4 + 3] = q.w;
    }
    const unsigned short* fb = featsb + ((size_t)tid * NBATCH + b) * NTIME + t0;
    float acc = 0.f;
    #pragma unroll
    for (int q4 = 0; q4 < 4; ++q4) {
        uint4 fv = *(const uint4*)(fb + q4 * 8);
        acc += bflo(fv.x) * er[q4 * 8 + 0] + bfhi(fv.x) * er[q4 * 8 + 1]
             + bflo(fv.y) * er[q4 * 8 + 2] + bfhi(fv.y) * er[q4 * 8 + 3]
             + bflo(fv.z) * er[q4 * 8 + 4] + bfhi(fv.z) * er[q4 * 8 + 5]
             + bflo(fv.w) * er[q4 * 8 + 6] + bfhi(fv.w) * er[q4 * 8 + 7];
    }
    atomicAdd(ctx_un + (size_t)b * NCH + tid, acc);
}

// ---------------------------------------------------------------------------
// Gates GEMM via MFMA: g2[j][b] = sum_k A[b][k]*Wgb[j][k], fp32 out.
// 24 blocks x 256. Blocks 0-11: A = ctx_un (fp32, UN-normalized -> bf16 in
// staging); blocks 12-23: A = h_bf (bf16, gl_lds16).
__global__ __launch_bounds__(256) void k_gmfma(const float* __restrict__ ctx_un,
                                               const unsigned short* __restrict__ h_bf,
                                               const unsigned short* __restrict__ Wgb,
                                               float* __restrict__ g2) {
    __shared__ unsigned short As[128 * 64];
    __shared__ unsigned short Bs[128 * 64];
    const int j0 = blockIdx.x * 128;
    const bool ctxp = (j0 < 1536);
    const int tid = threadIdx.x;
    const int lane = tid & 63;
    const int wid = __builtin_amdgcn_readfirstlane(tid >> 6);
    const int wb = wid & 1, wj = wid >> 1;
    const int l8 = lane >> 3, c8 = lane & 7;
    const int arow = tid & 127, ahalf = tid >> 7;
    f32x4 acc[4][4];
    #pragma unroll
    for (int i = 0; i < 4; ++i)
        #pragma unroll
        for (int j = 0; j < 4; ++j) acc[i][j] = (f32x4)0.f;

    for (int k0 = 0; k0 < 512; k0 += 64) {
        // B (weights): gl_lds16, 16 slots x 8 rows
        #pragma unroll
        for (int i = 0; i < 4; ++i) {
            int slot = wid * 4 + i;
            int row = slot * 8 + l8;
            gl_lds16(Wgb + (size_t)(j0 + row) * 512 + k0 + ((c8 ^ (row & 7)) << 3),
                     Bs + slot * 512);
        }
        // A (activations)
        if (ctxp) {
            #pragma unroll
            for (int i = 0; i < 4; ++i) {
                int ch = ahalf * 4 + i;
                const float* src = ctx_un + (size_t)arow * 512 + k0 + ch * 8;
                float4 a0 = *(const float4*)(src);
                float4 a1 = *(const float4*)(src + 4);
                uint4 o;
                o.x = pk2bf(a0.x, a0.y); o.y = pk2bf(a0.z, a0.w);
                o.z = pk2bf(a1.x, a1.y); o.w = pk2bf(a1.z, a1.w);
                *(uint4*)(As + arow * 64 + ((ch ^ (arow & 7)) << 3)) = o;
            }
        } else {
            #pragma unroll
            for (int i = 0; i < 4; ++i) {
                int slot = wid * 4 + i;
                int row = slot * 8 + l8;
                gl_lds16(h_bf + (size_t)row * 512 + k0 + ((c8 ^ (row & 7)) << 3),
                         As + slot * 512);
            }
        }
        __syncthreads();
        #pragma unroll
        for (int ks = 0; ks < 2; ++ks) {
            short8v a[4], b[4];
            #pragma unroll
            for (int f = 0; f < 4; ++f) {
                int rowa = wb * 64 + f * 16 + (lane & 15);
                int rowb = wj * 64 + f * 16 + (lane & 15);
                int ch = ks * 4 + (lane >> 4);
                a[f] = *(const short8v*)(As + rowa * 64 + ((ch ^ (rowa & 7)) << 3));
                b[f] = *(const short8v*)(Bs + rowb * 64 + ((ch ^ (rowb & 7)) << 3));
            }
            #pragma unroll
            for (int bf = 0; bf < 4; ++bf)
                #pragma unroll
                for (int jf = 0; jf < 4; ++jf)
                    acc[bf][jf] = __builtin_amdgcn_mfma_f32_16x16x32_bf16(
                        a[bf], b[jf], acc[bf][jf], 0, 0, 0);
        }
        __syncthreads();
    }
    #pragma unroll
    for (int bf = 0; bf < 4; ++bf) {
        int b = wb * 64 + bf * 16 + (lane >> 4) * 4;
        #pragma unroll
        for (int jf = 0; jf < 4; ++jf) {
            int j = j0 + wj * 64 + jf * 16 + (lane & 15);
            *(f32x4*)(g2 + (size_t)j * NBATCH + b) = acc[bf][jf];
        }
    }
}

// ---------------------------------------------------------------------------
// Fused GRU-combine (i-gates x 1/esum) + next hp; zeroes NEXT step's
// ctx_un/esum buffers (ping-pong -> no race with this step's readers).
__global__ __launch_bounds__(1024) void k_comb_hp(const float* __restrict__ g2,
                                                  const float* __restrict__ hprev,
                                                  float* __restrict__ hidn,
                                                  unsigned short* __restrict__ h_bf,
                                                  const float* __restrict__ bih,
                                                  const float* __restrict__ bhh,
                                                  const unsigned short* __restrict__ WTb,
                                                  const float* __restrict__ bh2h,
                                                  float* __restrict__ hp,
                                                  const float* __restrict__ esum_cur,
                                                  float* __restrict__ ctx_next,
                                                  float* __restrict__ esum_next) {
    __shared__ float h_s[4 * 512];
    __shared__ float scr2[16 * 4 * 16 * 4];
    const int blk = blockIdx.x;
    const int b0 = (blk >> 3) * 4;
    const int jbase = (blk & 7) * 64;
    const int tid = threadIdx.x;
    #pragma unroll
    for (int rep = 0; rep < 2; ++rep) {
        int idx = tid + rep * 1024;
        int bi = idx & 3, kk = idx >> 2;
        int b = b0 + bi;
        float inv = 1.f / esum_cur[b];
        float ir  = g2[(size_t)(0 * 512 + kk) * NBATCH + b] * inv + bih[kk];
        float iz  = g2[(size_t)(1 * 512 + kk) * NBATCH + b] * inv + bih[512 + kk];
        float in_ = g2[(size_t)(2 * 512 + kk) * NBATCH + b] * inv + bih[1024 + kk];
        float hr  = g2[(size_t)(3 * 512 + kk) * NBATCH + b] + bhh[kk];
        float hz  = g2[(size_t)(4 * 512 + kk) * NBATCH + b] + bhh[512 + kk];
        float hn  = g2[(size_t)(5 * 512 + kk) * NBATCH + b] + bhh[1024 + kk];
        float r = fast_sigmoid(ir + hr);
        float z = fast_sigmoid(iz + hz);
        float ng = fast_tanh(in_ + r * hn);
        float hv = hprev[(size_t)b * NH + kk];
        float hnew = (1.f - z) * ng + z * hv;
        h_s[bi * 512 + kk] = hnew;
        if ((blk & 7) == 0) {
            hidn[(size_t)b * NH + kk] = hnew;
            h_bf[(size_t)b * NH + kk] = f2bf(hnew);
        }
    }
    __syncthreads();
    {
        const int jq = tid & 15, bi = (tid >> 4) & 3, kq = tid >> 6;
        const int j = jbase + jq * 4;
        float4 acc = make_float4(0.f, 0.f, 0.f, 0.f);
        #pragma unroll 8
        for (int kk = 0; kk < 32; ++kk) {
            int k = kq * 32 + kk;
            uint2 wq = *(const uint2*)(WTb + (size_t)k * NH + j);
            float hv = h_s[bi * 512 + k];
            acc.x += hv * bflo(wq.x); acc.y += hv * bfhi(wq.x);
            acc.z += hv * bflo(wq.y); acc.w += hv * bfhi(wq.y);
        }
        *(float4*)&scr2[((kq * 4 + bi) * 16 + jq) * 4] = acc;
    }
    __syncthreads();
    if (tid < 64) {
        const int bi = tid >> 4, jq = tid & 15;
        float4 sum = make_float4(0.f, 0.f, 0.f, 0.f);
        #pragma unroll
        for (int kq = 0; kq < 16; ++kq) {
            float4 p = *(const float4*)&scr2[((kq * 4 + bi) * 16 + jq) * 4];
            sum.x += p.x; sum.y += p.y; sum.z += p.z; sum.w += p.w;
        }
        int j = jbase + jq * 4;
        float4 bb = *(const float4*)(bh2h + j);
        sum.x += bb.x; sum.y += bb.y; sum.z += bb.z; sum.w += bb.w;
        *(float4*)(hp + (size_t)(b0 + bi) * NH + j) = sum;
    }
    // zero next step's accumulation buffers
    {
        int idx = blk * 1024 + tid;       // 262144 >= 65536
        if (idx < 65536) ctx_next[idx] = 0.f;
        if (idx < 128)   esum_next[idx] = 0.f;
    }
}

// ---------------------------------------------------------------------------
__global__ __launch_bounds__(256) void k_gen(const float* __restrict__ hid,
                                             const float* __restrict__ Wgen,
                                             const float* __restrict__ bgen,
                                             float* __restrict__ out) {
    __shared__ float As[32][36];
    __shared__ float Bs[32][97];
    const int m0 = blockIdx.x * 32;
    const int tid = threadIdx.x;
    const int tx = tid & 31, ty = tid >> 5;
    float acc[4][3] = {};
    for (int k0 = 0; k0 < 512; k0 += 32) {
        {
            int mm = tid >> 3, kq = (tid & 7) << 2;
            int m = m0 + mm, s = m & 31, b = m >> 5;
            float4 v = *(const float4*)(hid + (size_t)(s + 1) * 65536 + b * 512 + k0 + kq);
            *(float4*)(&As[mm][kq]) = v;
        }
        #pragma unroll
        for (int i = 0; i < 3; ++i) {
            int f4 = tid + i * 256;
            int nn = f4 >> 3, kq = (f4 & 7) << 2;
            float4 v = *(const float4*)(Wgen + (size_t)nn * 512 + k0 + kq);
            Bs[kq + 0][nn] = v.x; Bs[kq + 1][nn] = v.y;
            Bs[kq + 2][nn] = v.z; Bs[kq + 3][nn] = v.w;
        }
        __syncthreads();
        #pragma unroll
        for (int kk = 0; kk < 32; ++kk) {
            float bv[3];
            #pragma unroll
            for (int j = 0; j < 3; ++j) bv[j] = Bs[kk][tx * 3 + j];
            #pragma unroll
            for (int i = 0; i < 4; ++i) {
                float a = As[ty * 4 + i][kk];
                #pragma unroll
                for (int j = 0; j < 3; ++j) acc[i][j] += a * bv[j];
            }
        }
        __syncthreads();
    }
    #pragma unroll
    for (int i = 0; i < 4; ++i)
        #pragma unroll
        for (int j = 0; j < 3; ++j)
            out[(size_t)(m0 + ty * 4 + i) * NOUT + tx * 3 + j] = acc[i][j] + bgen[tx * 3 + j];
}

// ---------------------------------------------------------------------------
extern "C" void kernel_launch(void* const* d_in, const int* in_sizes, int n_in,
                              void* d_out, int out_size, void* d_ws, size_t ws_size,
                              hipStream_t stream) {
    const float* feats  = (const float*)d_in[0];
    const float* Wi2h   = (const float*)d_in[2];
    const float* Wh2h   = (const float*)d_in[3];
    const float* bh2h   = (const float*)d_in[4];
    const float* Wscore = (const float*)d_in[5];
    const float* Wih    = (const float*)d_in[6];
    const float* Whh    = (const float*)d_in[7];
    const float* bih    = (const float*)d_in[8];
    const float* bhh    = (const float*)d_in[9];
    const float* Wgen   = (const float*)d_in[10];
    const float* bgen   = (const float*)d_in[11];
    float* out = (float*)d_out;

    // ws layout (float-slot offsets):
    float* ws = (float*)d_ws;
    unsigned short* fp_bf = (unsigned short*)ws;                 // 16,777,216 bf16
    float* hid    = ws + 8388608;                                // 2,162,688
    float* hp     = hid + 2162688;                               // 65,536
    float* ctx_un = hp + 65536;                                  // 131,072 (2 bufs)
    float* esum   = ctx_un + 131072;                             // 256 (2 bufs)
    float* Cbuf   = esum + 256;                                  // 16
    unsigned short* h_bf = (unsigned short*)(Cbuf + 16);         // 65,536 bf16
    unsigned short* WTb  = (unsigned short*)(Cbuf + 16 + 32768); // 262,144 bf16
    unsigned short* Wgb  = (unsigned short*)(Cbuf + 16 + 32768 + 131072);            // 1,572,864 bf16
    unsigned short* Wb   = (unsigned short*)(Cbuf + 16 + 32768 + 131072 + 786432);   // 262,144 bf16
    unsigned short* Fb   = (unsigned short*)(Cbuf + 16 + 32768 + 131072 + 786432 + 131072); // 16,777,216 bf16
    const size_t base_floats = 8388608 + 2162688 + 65536 + 131072 + 256 + 16
                             + 32768 + 131072 + 786432 + 131072 + 8388608;
    const bool big = ws_size >= (base_floats + 8388608) * sizeof(float);
    unsigned short* featsb = big ? (Fb + 16777216) : Fb;   // small-ws: reuse Fb after mfma

    float* g2 = out;               // 6*512*128 = 393216 = out_size (overwritten by k_gen)

    hipMemsetAsync(hid, 0, 65536 * sizeof(float), stream);            // h0 = 0
    hipMemsetAsync(h_bf, 0, 65536 * sizeof(unsigned short), stream);  // h0_bf = 0
    k_wt<<<256, 256, 0, stream>>>(Wh2h, WTb);
    k_w2bf<<<64, 256, 0, stream>>>(Wi2h, Wb);
    k_wg2bf<<<384, 256, 0, stream>>>(Wih, Whh, Wgb);
    if (big) {
        k_prep<<<4096, 256, 0, stream>>>(feats, featsb, Fb);
        k_fp_mfma<<<512, 256, 0, stream>>>(Wb, Fb, fp_bf);
    } else {
        k_feats2bf<<<4096, 256, 0, stream>>>(feats, Fb);
        k_fp_mfma<<<512, 256, 0, stream>>>(Wb, Fb, fp_bf);
        k_fcopy<<<4096, 1024, 0, stream>>>(feats, featsb);
    }
    k_init<<<64, 1024, 0, stream>>>(bh2h, Wscore, hp, ctx_un, esum, Cbuf);

    for (int s = 0; s < NSTEPS; ++s) {
        const float* h = hid + (size_t)s * 65536;
        float* hn      = hid + (size_t)(s + 1) * 65536;
        float* ctxc = ctx_un + (size_t)(s & 1) * 65536;
        float* esc  = esum + (size_t)(s & 1) * 128;
        float* ctxn = ctx_un + (size_t)((s + 1) & 1) * 65536;
        float* esn  = esum + (size_t)((s + 1) & 1) * 128;
        k_ectx<<<1024, 512, 0, stream>>>(fp_bf, featsb, hp, Wscore, Cbuf, ctxc, esc);
        k_gmfma<<<24, 256, 0, stream>>>(ctxc, h_bf, Wgb, g2);
        k_comb_hp<<<256, 1024, 0, stream>>>(g2, h, hn, h_bf, bih, bhh, WTb, bh2h,
                                            hp, esc, ctxn, esn);
    }
    k_gen<<<128, 256, 0, stream>>>(hid, Wgen, bgen, out);
}

// Round 13
// 1565.116 us; speedup vs baseline: 2.8597x; 1.1442x over previous
//
#include <hip/hip_runtime.h>
#include <math.h>

#define NBATCH 128
#define NTIME  256
#define NCH    512
#define NH     512
#define NSTEPS 32
#define NOUT   96
#define MTOT   32768

typedef __attribute__((ext_vector_type(8))) short short8v;
typedef __attribute__((ext_vector_type(4))) float f32x4;

typedef const __attribute__((address_space(1))) unsigned int g_as_uint;
typedef __attribute__((address_space(3))) unsigned int l_as_uint;

__device__ __forceinline__ void gl_lds16(const void* g, void* l) {
    __builtin_amdgcn_global_load_lds((g_as_uint*)g, (l_as_uint*)l, 16, 0, 0);
}

__device__ __forceinline__ float fast_tanh(float x) {
    x = fminf(fmaxf(x, -30.f), 30.f);
    float u = __expf(2.f * x);
    return (u - 1.f) / (u + 1.f);
}
__device__ __forceinline__ float fast_sigmoid(float x) {
    x = fminf(fmaxf(x, -30.f), 30.f);
    return 1.f / (1.f + __expf(-x));
}
__device__ __forceinline__ float wave_reduce_sum(float s) {
    #pragma unroll
    for (int off = 32; off; off >>= 1) s += __shfl_xor(s, off, 64);
    return s;
}
__device__ __forceinline__ float wave_reduce_max(float s) {
    #pragma unroll
    for (int off = 32; off; off >>= 1) s = fmaxf(s, __shfl_xor(s, off, 64));
    return s;
}
__device__ __forceinline__ unsigned short f2bf(float f) {
    unsigned u = __builtin_bit_cast(unsigned, f);
    return (unsigned short)((u + 0x7FFFu + ((u >> 16) & 1u)) >> 16);
}
__device__ __forceinline__ float bflo(unsigned u) {
    return __builtin_bit_cast(float, u << 16);
}
__device__ __forceinline__ float bfhi(unsigned u) {
    return __builtin_bit_cast(float, u & 0xFFFF0000u);
}

// ---------------------------------------------------------------------------
// Wi2h fp32 [512][512] -> bf16 same layout
__global__ __launch_bounds__(256) void k_w2bf(const float* __restrict__ W,
                                              unsigned short* __restrict__ Wb) {
    #pragma unroll
    for (int r = 0; r < 4; ++r) {
        int idx = (blockIdx.x * 256 + threadIdx.x) + r * 16384;
        float4 v = *(const float4*)(W + (size_t)idx * 4);
        ushort4 o;
        o.x = f2bf(v.x); o.y = f2bf(v.y); o.z = f2bf(v.z); o.w = f2bf(v.w);
        *(ushort4*)(Wb + (size_t)idx * 4) = o;
    }
}

// ---------------------------------------------------------------------------
// Wgb = concat(Wih, Whh) fp32 [3072][512] -> bf16. 384 blocks x 256, 4 f4 each.
__global__ __launch_bounds__(256) void k_wg2bf(const float* __restrict__ Wih,
                                               const float* __restrict__ Whh,
                                               unsigned short* __restrict__ Wgb) {
    #pragma unroll
    for (int r = 0; r < 4; ++r) {
        int idx = (blockIdx.x * 256 + threadIdx.x) + r * 98304;   // f4 idx, 393216 total
        const float* src = (idx < 196608) ? (Wih + (size_t)idx * 4)
                                          : (Whh + (size_t)(idx - 196608) * 4);
        float4 v = *(const float4*)src;
        ushort4 o;
        o.x = f2bf(v.x); o.y = f2bf(v.y); o.z = f2bf(v.z); o.w = f2bf(v.w);
        *(ushort4*)(Wgb + (size_t)idx * 4) = o;
    }
}

// ---------------------------------------------------------------------------
// FUSED feats prep (big-ws path): read feats [k][m] fp32 once; write
// featsb = bf16 same layout AND Fb = bf16 transposed [m][k]. 4096 x 256.
__global__ __launch_bounds__(256) void k_prep(const float* __restrict__ feats,
                                              unsigned short* __restrict__ featsb,
                                              unsigned short* __restrict__ Fb) {
    __shared__ float tl[64][65];
    const int m0 = (blockIdx.x & 511) * 64;
    const int k0 = (blockIdx.x >> 9) * 64;
    const int tid = threadIdx.x;
    #pragma unroll
    for (int p = 0; p < 4; ++p) {
        int fid = tid + p * 256;
        int row = fid >> 4, c4 = fid & 15;
        float4 v = *(const float4*)(feats + (size_t)(k0 + row) * MTOT + m0 + c4 * 4);
        tl[row][c4 * 4 + 0] = v.x; tl[row][c4 * 4 + 1] = v.y;
        tl[row][c4 * 4 + 2] = v.z; tl[row][c4 * 4 + 3] = v.w;
        ushort4 o;
        o.x = f2bf(v.x); o.y = f2bf(v.y); o.z = f2bf(v.z); o.w = f2bf(v.w);
        *(ushort4*)(featsb + (size_t)(k0 + row) * MTOT + m0 + c4 * 4) = o;
    }
    __syncthreads();
    #pragma unroll
    for (int p = 0; p < 4; ++p) {
        int cid = tid + p * 256;
        int mm = cid >> 4, ch = cid & 15;
        ushort4 o;
        o.x = f2bf(tl[ch * 4 + 0][mm]);
        o.y = f2bf(tl[ch * 4 + 1][mm]);
        o.z = f2bf(tl[ch * 4 + 2][mm]);
        o.w = f2bf(tl[ch * 4 + 3][mm]);
        *(ushort4*)(Fb + (size_t)(m0 + mm) * 512 + k0 + ch * 4) = o;
    }
}

// ---------------------------------------------------------------------------
// Fallback path (small ws): feats -> Fb[m][k] bf16 (transpose)
__global__ __launch_bounds__(256) void k_feats2bf(const float* __restrict__ feats,
                                                  unsigned short* __restrict__ Fb) {
    __shared__ float tl[64][65];
    const int m0 = (blockIdx.x & 511) * 64;
    const int k0 = (blockIdx.x >> 9) * 64;
    const int tid = threadIdx.x;
    #pragma unroll
    for (int p = 0; p < 4; ++p) {
        int fid = tid + p * 256;
        int row = fid >> 4, c4 = fid & 15;
        float4 v = *(const float4*)(feats + (size_t)(k0 + row) * MTOT + m0 + c4 * 4);
        tl[row][c4 * 4 + 0] = v.x; tl[row][c4 * 4 + 1] = v.y;
        tl[row][c4 * 4 + 2] = v.z; tl[row][c4 * 4 + 3] = v.w;
    }
    __syncthreads();
    #pragma unroll
    for (int p = 0; p < 4; ++p) {
        int cid = tid + p * 256;
        int mm = cid >> 4, ch = cid & 15;
        ushort4 o;
        o.x = f2bf(tl[ch * 4 + 0][mm]);
        o.y = f2bf(tl[ch * 4 + 1][mm]);
        o.z = f2bf(tl[ch * 4 + 2][mm]);
        o.w = f2bf(tl[ch * 4 + 3][mm]);
        *(ushort4*)(Fb + (size_t)(m0 + mm) * 512 + k0 + ch * 4) = o;
    }
}

// Fallback path: feats fp32 [c][b][t] -> bf16 same layout (after k_fp_mfma)
__global__ __launch_bounds__(1024) void k_fcopy(const float* __restrict__ f,
                                                unsigned short* __restrict__ o) {
    int gid = blockIdx.x * 1024 + threadIdx.x;
    float4 v = *(const float4*)(f + (size_t)gid * 4);
    ushort4 s;
    s.x = f2bf(v.x); s.y = f2bf(v.y); s.z = f2bf(v.z); s.w = f2bf(v.w);
    *(ushort4*)(o + (size_t)gid * 4) = s;
}

// ---------------------------------------------------------------------------
// MFMA GEMM: fp[m][h] = sum_k featsT[m][k] * Wi2h[h][k]  (bf16 in, bf16 out)
// Staging via global_load_lds width=16: linear LDS dest, swizzle on SOURCE addr
// (XOR involution; read side unchanged).
__global__ __launch_bounds__(256) void k_fp_mfma(const unsigned short* __restrict__ Wb,
                                                 const unsigned short* __restrict__ Fb,
                                                 unsigned short* __restrict__ fp_bf) {
    __shared__ char SB[49152];
    unsigned short* As = (unsigned short*)SB;            // [128 h][64 k]
    unsigned short* Bs = (unsigned short*)(SB + 16384);  // [256 m][64 k]
    float* tl = (float*)SB;                              // [256 m][33]
    const int m0 = (blockIdx.x & 127) * 256;
    const int h0 = (blockIdx.x >> 7) * 128;
    const int tid = threadIdx.x;
    const int lane = tid & 63;
    const int wid = __builtin_amdgcn_readfirstlane(tid >> 6);
    const int wh = wid & 1, wm = wid >> 1;
    const int l8 = lane >> 3, c8 = lane & 7;
    f32x4 acc[4][8];
    #pragma unroll
    for (int i = 0; i < 4; ++i)
        #pragma unroll
        for (int j = 0; j < 8; ++j) acc[i][j] = (f32x4)0.f;

    for (int k0 = 0; k0 < 512; k0 += 64) {
        // A: 16 slots x 1KB (8 rows each); wave handles 4
        #pragma unroll
        for (int i = 0; i < 4; ++i) {
            int slot = wid * 4 + i;
            int row = slot * 8 + l8;
            gl_lds16(Wb + (size_t)(h0 + row) * 512 + k0 + ((c8 ^ (row & 7)) << 3),
                     As + slot * 512);
        }
        // B: 32 slots; wave handles 8
        #pragma unroll
        for (int i = 0; i < 8; ++i) {
            int slot = wid * 8 + i;
            int row = slot * 8 + l8;
            gl_lds16(Fb + (size_t)(m0 + row) * 512 + k0 + ((c8 ^ (row & 7)) << 3),
                     Bs + slot * 512);
        }
        __syncthreads();
        #pragma unroll
        for (int ks = 0; ks < 2; ++ks) {
            short8v a[4], b[8];
            #pragma unroll
            for (int hf = 0; hf < 4; ++hf) {
                int row = wh * 64 + hf * 16 + (lane & 15);
                int ch = ks * 4 + (lane >> 4);
                a[hf] = *(const short8v*)(As + row * 64 + ((ch ^ (row & 7)) << 3));
            }
            #pragma unroll
            for (int mf = 0; mf < 8; ++mf) {
                int row = wm * 128 + mf * 16 + (lane & 15);
                int ch = ks * 4 + (lane >> 4);
                b[mf] = *(const short8v*)(Bs + row * 64 + ((ch ^ (row & 7)) << 3));
            }
            #pragma unroll
            for (int hf = 0; hf < 4; ++hf)
                #pragma unroll
                for (int mf = 0; mf < 8; ++mf)
                    acc[hf][mf] = __builtin_amdgcn_mfma_f32_16x16x32_bf16(
                        a[hf], b[mf], acc[hf][mf], 0, 0, 0);
        }
        __syncthreads();
    }
    #pragma unroll
    for (int hf = 0; hf < 4; ++hf) {
        #pragma unroll
        for (int mf = 0; mf < 8; ++mf) {
            int ml = wm * 128 + mf * 16 + (lane & 15);
            int col = wh * 16 + (lane >> 4) * 4;
            tl[ml * 33 + col + 0] = acc[hf][mf][0];
            tl[ml * 33 + col + 1] = acc[hf][mf][1];
            tl[ml * 33 + col + 2] = acc[hf][mf][2];
            tl[ml * 33 + col + 3] = acc[hf][mf][3];
        }
        __syncthreads();
        #pragma unroll
        for (int mi = 0; mi < 8; ++mi) {
            int ml = (tid >> 3) + mi * 32;
            int hl4 = (tid & 7) * 4;
            float v0 = tl[ml * 33 + hl4 + 0];
            float v1 = tl[ml * 33 + hl4 + 1];
            float v2 = tl[ml * 33 + hl4 + 2];
            float v3 = tl[ml * 33 + hl4 + 3];
            int hg = h0 + ((hl4 < 16) ? (hf * 16 + hl4) : (64 + hf * 16 + hl4 - 16));
            ushort4 o;
            o.x = f2bf(v0); o.y = f2bf(v1); o.z = f2bf(v2); o.w = f2bf(v3);
            *(ushort4*)(fp_bf + (size_t)(m0 + ml) * 512 + hg) = o;
        }
        __syncthreads();
    }
}

// ---------------------------------------------------------------------------
// Transpose Wh2h[512][512] -> WTb[k][j] bf16  (one-time)
__global__ __launch_bounds__(256) void k_wt(const float* __restrict__ W,
                                            unsigned short* __restrict__ WTb) {
    __shared__ float tl[32][33];
    const int bi = blockIdx.x & 15, bj = blockIdx.x >> 4;
    const int tx = threadIdx.x & 31, ty8 = threadIdx.x >> 5;
    #pragma unroll
    for (int i = 0; i < 4; ++i) {
        int r = ty8 * 4 + i;
        tl[r][tx] = W[(size_t)(bj * 32 + r) * NH + bi * 32 + tx];
    }
    __syncthreads();
    #pragma unroll
    for (int i = 0; i < 4; ++i) {
        int c = ty8 * 4 + i;
        WTb[(size_t)(bi * 32 + c) * NH + bj * 32 + tx] = f2bf(tl[tx][c]);
    }
}

// ---------------------------------------------------------------------------
__global__ __launch_bounds__(1024) void k_hp0(const float* __restrict__ bh2h,
                                              float* __restrict__ hp) {
    int i = blockIdx.x * 1024 + threadIdx.x;
    hp[i] = bh2h[i & 511];
}

// ---------------------------------------------------------------------------
// e[b][t] = sum_h tanh(fp[b][t][h] + hp[b][h]) * wscore[h]   (fp in bf16)
// 1024 blocks x 512: b = blk>>3, t0 = (blk&7)*32; wave -> 4 t's.
__global__ __launch_bounds__(512) void k_e(const unsigned short* __restrict__ fp_bf,
                                           const float* __restrict__ hp,
                                           const float* __restrict__ wscore,
                                           float* __restrict__ e) {
    const int b = blockIdx.x >> 3;
    const int t0 = (blockIdx.x & 7) * 32;
    const int tid = threadIdx.x;
    const int lane = tid & 63, w = tid >> 6;
    float4 h0 = *(const float4*)(hp + (size_t)b * NH + lane * 8);
    float4 h1 = *(const float4*)(hp + (size_t)b * NH + lane * 8 + 4);
    float4 w0 = *(const float4*)(wscore + lane * 8);
    float4 w1 = *(const float4*)(wscore + lane * 8 + 4);
    const unsigned short* base = fp_bf + (size_t)(b * NTIME + t0 + w * 4) * NH + lane * 8;
    uint4 v0 = *(const uint4*)(base);
    uint4 v1 = *(const uint4*)(base + NH);
    uint4 v2 = *(const uint4*)(base + 2 * NH);
    uint4 v3 = *(const uint4*)(base + 3 * NH);
    uint4 vv[4] = {v0, v1, v2, v3};
    #pragma unroll
    for (int it = 0; it < 4; ++it) {
        uint4 v = vv[it];
        float s = fast_tanh(bflo(v.x) + h0.x) * w0.x + fast_tanh(bfhi(v.x) + h0.y) * w0.y +
                  fast_tanh(bflo(v.y) + h0.z) * w0.z + fast_tanh(bfhi(v.y) + h0.w) * w0.w +
                  fast_tanh(bflo(v.z) + h1.x) * w1.x + fast_tanh(bfhi(v.z) + h1.y) * w1.y +
                  fast_tanh(bflo(v.w) + h1.z) * w1.z + fast_tanh(bfhi(v.w) + h1.w) * w1.w;
        s = wave_reduce_sum(s);
        if (lane == 0) e[b * NTIME + t0 + w * 4 + it] = s;
    }
}

// ---------------------------------------------------------------------------
// softmax(e[b]) + ctx[b][c] = sum_t featsb[c][b][t]*alpha[t] -> ctx_bf (bf16)
// 1024 blocks x 512: b = blk>>3, c0 = (blk&7)*64; wave -> 8 c's.
__global__ __launch_bounds__(512) void k_ctx2(const float* __restrict__ e,
                                              const unsigned short* __restrict__ featsb,
                                              unsigned short* __restrict__ ctx_bf) {
    __shared__ float als[256];
    __shared__ float red[8];
    const int b = blockIdx.x >> 3;
    const int c0 = (blockIdx.x & 7) * 64;
    const int tid = threadIdx.x;
    const int lane = tid & 63, w = tid >> 6;
    float v = (tid < 256) ? e[b * NTIME + tid] : -3.4e38f;
    float m = wave_reduce_max(v);
    if (lane == 0) red[w] = m;
    __syncthreads();
    m = red[0];
    #pragma unroll
    for (int i = 1; i < 8; ++i) m = fmaxf(m, red[i]);
    float ex = (tid < 256) ? __expf(v - m) : 0.f;
    float s = wave_reduce_sum(ex);
    __syncthreads();
    if (lane == 0) red[w] = s;
    __syncthreads();
    s = 0.f;
    #pragma unroll
    for (int i = 0; i < 8; ++i) s += red[i];
    if (tid < 256) als[tid] = ex / s;
    __syncthreads();

    float4 al = *(const float4*)&als[lane * 4];
    #pragma unroll
    for (int cc = 0; cc < 8; ++cc) {
        int c = c0 + w * 8 + cc;
        uint2 fv = *(const uint2*)(featsb + (size_t)(c * NBATCH + b) * NTIME + lane * 4);
        float sc = bflo(fv.x) * al.x + bfhi(fv.x) * al.y +
                   bflo(fv.y) * al.z + bfhi(fv.y) * al.w;
        sc = wave_reduce_sum(sc);
        if (lane == 0) ctx_bf[(size_t)b * NCH + c] = f2bf(sc);
    }
}

// ---------------------------------------------------------------------------
// Gates GEMM via MFMA: g2[j][b] = sum_k A[b][k] * Wgb[j][k], fp32 out.
// 24 blocks x 256; block tile 128b x 128j, BK=64; global_load_lds staging.
__global__ __launch_bounds__(256) void k_gmfma(const unsigned short* __restrict__ ctx_bf,
                                               const unsigned short* __restrict__ h_bf,
                                               const unsigned short* __restrict__ Wgb,
                                               float* __restrict__ g2) {
    __shared__ unsigned short As[128 * 64];   // activations [128 b][64 k]
    __shared__ unsigned short Bs[128 * 64];   // weights     [128 j][64 k]
    const int j0 = blockIdx.x * 128;
    const unsigned short* A = (j0 < 1536) ? ctx_bf : h_bf;
    const int tid = threadIdx.x;
    const int lane = tid & 63;
    const int wid = __builtin_amdgcn_readfirstlane(tid >> 6);
    const int wb = wid & 1, wj = wid >> 1;
    const int l8 = lane >> 3, c8 = lane & 7;
    f32x4 acc[4][4];
    #pragma unroll
    for (int i = 0; i < 4; ++i)
        #pragma unroll
        for (int j = 0; j < 4; ++j) acc[i][j] = (f32x4)0.f;

    for (int k0 = 0; k0 < 512; k0 += 64) {
        #pragma unroll
        for (int i = 0; i < 4; ++i) {
            int slot = wid * 4 + i;
            int row = slot * 8 + l8;
            int src_off = (c8 ^ (row & 7)) << 3;
            gl_lds16(A + (size_t)row * 512 + k0 + src_off, As + slot * 512);
            gl_lds16(Wgb + (size_t)(j0 + row) * 512 + k0 + src_off, Bs + slot * 512);
        }
        __syncthreads();
        #pragma unroll
        for (int ks = 0; ks < 2; ++ks) {
            short8v a[4], b[4];
            #pragma unroll
            for (int f = 0; f < 4; ++f) {
                int rowa = wb * 64 + f * 16 + (lane & 15);
                int rowb = wj * 64 + f * 16 + (lane & 15);
                int ch = ks * 4 + (lane >> 4);
                a[f] = *(const short8v*)(As + rowa * 64 + ((ch ^ (rowa & 7)) << 3));
                b[f] = *(const short8v*)(Bs + rowb * 64 + ((ch ^ (rowb & 7)) << 3));
            }
            #pragma unroll
            for (int bf = 0; bf < 4; ++bf)
                #pragma unroll
                for (int jf = 0; jf < 4; ++jf)
                    acc[bf][jf] = __builtin_amdgcn_mfma_f32_16x16x32_bf16(
                        a[bf], b[jf], acc[bf][jf], 0, 0, 0);
        }
        __syncthreads();
    }
    #pragma unroll
    for (int bf = 0; bf < 4; ++bf) {
        int b = wb * 64 + bf * 16 + (lane >> 4) * 4;
        #pragma unroll
        for (int jf = 0; jf < 4; ++jf) {
            int j = j0 + wj * 64 + jf * 16 + (lane & 15);
            *(f32x4*)(g2 + (size_t)j * NBATCH + b) = acc[bf][jf];
        }
    }
}

// ---------------------------------------------------------------------------
// Fused GRU-combine + next hp (WTb bf16). Writes h_bf for next step's gates.
__global__ __launch_bounds__(1024) void k_comb_hp(const float* __restrict__ g2,
                                                  const float* __restrict__ hprev,
                                                  float* __restrict__ hidn,
                                                  unsigned short* __restrict__ h_bf,
                                                  const float* __restrict__ bih,
                                                  const float* __restrict__ bhh,
                                                  const unsigned short* __restrict__ WTb,
                                                  const float* __restrict__ bh2h,
                                                  float* __restrict__ hp) {
    __shared__ float h_s[4 * 512];
    __shared__ float scr2[16 * 4 * 16 * 4];
    const int blk = blockIdx.x;
    const int b0 = (blk >> 3) * 4;
    const int jbase = (blk & 7) * 64;
    const int tid = threadIdx.x;
    #pragma unroll
    for (int rep = 0; rep < 2; ++rep) {
        int idx = tid + rep * 1024;
        int bi = idx & 3, kk = idx >> 2;
        int b = b0 + bi;
        float ir  = g2[(size_t)(0 * 512 + kk) * NBATCH + b] + bih[kk];
        float iz  = g2[(size_t)(1 * 512 + kk) * NBATCH + b] + bih[512 + kk];
        float in_ = g2[(size_t)(2 * 512 + kk) * NBATCH + b] + bih[1024 + kk];
        float hr  = g2[(size_t)(3 * 512 + kk) * NBATCH + b] + bhh[kk];
        float hz  = g2[(size_t)(4 * 512 + kk) * NBATCH + b] + bhh[512 + kk];
        float hn  = g2[(size_t)(5 * 512 + kk) * NBATCH + b] + bhh[1024 + kk];
        float r = fast_sigmoid(ir + hr);
        float z = fast_sigmoid(iz + hz);
        float ng = fast_tanh(in_ + r * hn);
        float hv = hprev[(size_t)b * NH + kk];
        float hnew = (1.f - z) * ng + z * hv;
        h_s[bi * 512 + kk] = hnew;
        if ((blk & 7) == 0) {
            hidn[(size_t)b * NH + kk] = hnew;
            h_bf[(size_t)b * NH + kk] = f2bf(hnew);
        }
    }
    __syncthreads();
    {
        const int jq = tid & 15, bi = (tid >> 4) & 3, kq = tid >> 6;
        const int j = jbase + jq * 4;
        float4 acc = make_float4(0.f, 0.f, 0.f, 0.f);
        #pragma unroll 8
        for (int kk = 0; kk < 32; ++kk) {
            int k = kq * 32 + kk;
            uint2 wq = *(const uint2*)(WTb + (size_t)k * NH + j);
            float hv = h_s[bi * 512 + k];
            acc.x += hv * bflo(wq.x); acc.y += hv * bfhi(wq.x);
            acc.z += hv * bflo(wq.y); acc.w += hv * bfhi(wq.y);
        }
        *(float4*)&scr2[((kq * 4 + bi) * 16 + jq) * 4] = acc;
    }
    __syncthreads();
    if (tid < 64) {
        const int bi = tid >> 4, jq = tid & 15;
        float4 sum = make_float4(0.f, 0.f, 0.f, 0.f);
        #pragma unroll
        for (int kq = 0; kq < 16; ++kq) {
            float4 p = *(const float4*)&scr2[((kq * 4 + bi) * 16 + jq) * 4];
            sum.x += p.x; sum.y += p.y; sum.z += p.z; sum.w += p.w;
        }
        int j = jbase + jq * 4;
        float4 bb = *(const float4*)(bh2h + j);
        sum.x += bb.x; sum.y += bb.y; sum.z += bb.z; sum.w += bb.w;
        *(float4*)(hp + (size_t)(b0 + bi) * NH + j) = sum;
    }
}

// ---------------------------------------------------------------------------
__global__ __launch_bounds__(256) void k_gen(const float* __restrict__ hid,
                                             const float* __restrict__ Wgen,
                                             const float* __restrict__ bgen,
                                             float* __restrict__ out) {
    __shared__ float As[32][36];
    __shared__ float Bs[32][97];
    const int m0 = blockIdx.x * 32;
    const int tid = threadIdx.x;
    const int tx = tid & 31, ty = tid >> 5;
    float acc[4][3] = {};
    for (int k0 = 0; k0 < 512; k0 += 32) {
        {
            int mm = tid >> 3, kq = (tid & 7) << 2;
            int m = m0 + mm, s = m & 31, b = m >> 5;
            float4 v = *(const float4*)(hid + (size_t)(s + 1) * 65536 + b * 512 + k0 + kq);
            *(float4*)(&As[mm][kq]) = v;
        }
        #pragma unroll
        for (int i = 0; i < 3; ++i) {
            int f4 = tid + i * 256;
            int nn = f4 >> 3, kq = (f4 & 7) << 2;
            float4 v = *(const float4*)(Wgen + (size_t)nn * 512 + k0 + kq);
            Bs[kq + 0][nn] = v.x; Bs[kq + 1][nn] = v.y;
            Bs[kq + 2][nn] = v.z; Bs[kq + 3][nn] = v.w;
        }
        __syncthreads();
        #pragma unroll
        for (int kk = 0; kk < 32; ++kk) {
            float bv[3];
            #pragma unroll
            for (int j = 0; j < 3; ++j) bv[j] = Bs[kk][tx * 3 + j];
            #pragma unroll
            for (int i = 0; i < 4; ++i) {
                float a = As[ty * 4 + i][kk];
                #pragma unroll
                for (int j = 0; j < 3; ++j) acc[i][j] += a * bv[j];
            }
        }
        __syncthreads();
    }
    #pragma unroll
    for (int i = 0; i < 4; ++i)
        #pragma unroll
        for (int j = 0; j < 3; ++j)
            out[(size_t)(m0 + ty * 4 + i) * NOUT + tx * 3 + j] = acc[i][j] + bgen[tx * 3 + j];
}

// ---------------------------------------------------------------------------
extern "C" void kernel_launch(void* const* d_in, const int* in_sizes, int n_in,
                              void* d_out, int out_size, void* d_ws, size_t ws_size,
                              hipStream_t stream) {
    const float* feats  = (const float*)d_in[0];
    const float* Wi2h   = (const float*)d_in[2];
    const float* Wh2h   = (const float*)d_in[3];
    const float* bh2h   = (const float*)d_in[4];
    const float* Wscore = (const float*)d_in[5];
    const float* Wih    = (const float*)d_in[6];
    const float* Whh    = (const float*)d_in[7];
    const float* bih    = (const float*)d_in[8];
    const float* bhh    = (const float*)d_in[9];
    const float* Wgen   = (const float*)d_in[10];
    const float* bgen   = (const float*)d_in[11];
    float* out = (float*)d_out;

    // ws layout (float-slot offsets):
    // base (80.5 MB): fp_bf | hid | hp | ctx_bf | h_bf | WTb | Wgb | Wb | Fb
    // big (+32 MB): featsb gets its own buffer after Fb -> fused k_prep path.
    float* ws  = (float*)d_ws;
    unsigned short* fp_bf  = (unsigned short*)ws;                        // 16,777,216 bf16
    float*          hid    = ws + 8388608;                               // 2,162,688 f32
    float*          hpctx  = hid + 2162688;                              // 65,536 f32
    unsigned short* ctx_bf = (unsigned short*)(hpctx + 65536);           // 65,536 bf16
    unsigned short* h_bf   = (unsigned short*)(hpctx + 65536 + 32768);   // 65,536 bf16
    unsigned short* WTb    = (unsigned short*)(hpctx + 65536 + 65536);   // 262,144 bf16
    unsigned short* Wgb    = (unsigned short*)(hpctx + 65536 + 65536 + 131072);           // 1,572,864 bf16
    unsigned short* Wb     = (unsigned short*)(hpctx + 65536 + 65536 + 131072 + 786432);  // 262,144 bf16
    unsigned short* Fb     = (unsigned short*)(hpctx + 65536 + 65536 + 131072 + 786432 + 131072); // 16,777,216 bf16
    const size_t base_floats = 8388608 + 2162688 + 65536 + 32768 + 32768 + 131072 + 786432 + 131072 + 8388608;
    const bool big = ws_size >= (base_floats + 8388608) * sizeof(float);
    unsigned short* featsb = big ? (Fb + 16777216) : Fb;  // small-ws: reuse Fb after mfma

    float* e  = out;                // aliases g2 head; disjoint lifetimes
    float* g2 = out;                // 6*512*128 = 393216 = out_size

    hipMemsetAsync(hid, 0, 65536 * sizeof(float), stream);           // h0 = 0
    hipMemsetAsync(h_bf, 0, 65536 * sizeof(unsigned short), stream); // h0_bf = 0
    k_wt<<<256, 256, 0, stream>>>(Wh2h, WTb);
    k_w2bf<<<64, 256, 0, stream>>>(Wi2h, Wb);
    k_wg2bf<<<384, 256, 0, stream>>>(Wih, Whh, Wgb);
    if (big) {
        k_prep<<<4096, 256, 0, stream>>>(feats, featsb, Fb);
        k_fp_mfma<<<512, 256, 0, stream>>>(Wb, Fb, fp_bf);
    } else {
        k_feats2bf<<<4096, 256, 0, stream>>>(feats, Fb);
        k_fp_mfma<<<512, 256, 0, stream>>>(Wb, Fb, fp_bf);
        k_fcopy<<<4096, 1024, 0, stream>>>(feats, featsb);   // after mfma: Fb dead
    }
    k_hp0<<<64, 1024, 0, stream>>>(bh2h, hpctx);

    for (int s = 0; s < NSTEPS; ++s) {
        const float* h = hid + (size_t)s * 65536;
        float* hn      = hid + (size_t)(s + 1) * 65536;
        k_e<<<1024, 512, 0, stream>>>(fp_bf, hpctx, Wscore, e);
        k_ctx2<<<1024, 512, 0, stream>>>(e, featsb, ctx_bf);
        k_gmfma<<<24, 256, 0, stream>>>(ctx_bf, h_bf, Wgb, g2);
        k_comb_hp<<<256, 1024, 0, stream>>>(g2, h, hn, h_bf, bih, bhh, WTb, bh2h, hpctx);
    }
    k_gen<<<128, 256, 0, stream>>>(hid, Wgen, bgen, out);
}